// Round 1
// baseline (499.119 us; speedup 1.0000x reference)
//
#include <hip/hip_runtime.h>

// ---- problem constants ----
#define T_TOK   2048
#define HID     2048
#define NHEADS  32
#define NKV     4
#define HD      128
#define QSZ     4096          // 32*128
#define KVSZ    512           // 4*128
#define QKVW    5120          // QSZ + 2*KVSZ

typedef unsigned short u16;
typedef __bf16 bf16x8 __attribute__((ext_vector_type(8)));
typedef float  f32x4  __attribute__((ext_vector_type(4)));

__device__ __forceinline__ u16 f2bf(float f) {
  unsigned int u = __float_as_uint(f);
  u += 0x7fffu + ((u >> 16) & 1u);   // RNE
  return (u16)(u >> 16);
}

// async 16B global -> LDS (wave-uniform base + lane*16 semantics)
__device__ __forceinline__ void gl2lds16(const void* g, void* l) {
  __builtin_amdgcn_global_load_lds(
      (const __attribute__((address_space(1))) unsigned int*)g,
      (__attribute__((address_space(3))) unsigned int*)l, 16, 0, 0);
}

// ---------------- fused fp32 -> bf16 convert (3 arrays, one launch) ---------
__global__ void cvt3_f32_bf16(const float* __restrict__ in0, u16* __restrict__ o0, int n0,
                              const float* __restrict__ in1, u16* __restrict__ o1, int n1,
                              const float* __restrict__ in2, u16* __restrict__ o2, int n2) {
  int i = blockIdx.x * blockDim.x + threadIdx.x;
  const float* in; u16* out;
  if (i < n0)            { in = in0; out = o0; }
  else if (i < n0 + n1)  { in = in1; out = o1; i -= n0; }
  else if (i < n0+n1+n2) { in = in2; out = o2; i -= n0 + n1; }
  else return;
  float4 v = ((const float4*)in)[i];
  ushort4 o;
  o.x = f2bf(v.x); o.y = f2bf(v.y); o.z = f2bf(v.z); o.w = f2bf(v.w);
  ((ushort4*)out)[i] = o;
}

// ---------------- NT GEMM: C[m][n] = sum_k A[m][k]*B[n][k] ----------------
template<int BM>
__launch_bounds__(256, 2)
__global__ void gemm_nt(const u16* __restrict__ A, const u16* __restrict__ B,
                        float* __restrict__ C, int M, int N, int K) {
  constexpr int MI = BM / 32;          // m-tiles per wave
  __shared__ __align__(16) u16 As[BM * 32];
  __shared__ __align__(16) u16 Bs[128 * 32];
  const int tid  = threadIdx.x;
  const int wave = tid >> 6, lane = tid & 63;
  const int l15  = lane & 15, quad = lane >> 4;
  const int wr   = wave >> 1, wc = wave & 1;

  const u16* Ab = A + (size_t)blockIdx.y * BM * K;
  const u16* Bb = B + (size_t)blockIdx.x * 128 * K;

  f32x4 acc[MI][4];
#pragma unroll
  for (int i = 0; i < MI; i++)
#pragma unroll
    for (int j = 0; j < 4; j++) acc[i][j] = (f32x4){0.f, 0.f, 0.f, 0.f};

  constexpr int ACH = BM * 32 / 8;     // 16B chunks in A tile
  for (int k0 = 0; k0 < K; k0 += 32) {
#pragma unroll
    for (int s = 0; s < (ACH + 512) / 256; s++) {
      int c = tid + s * 256;
      if (c < ACH) {
        int row = c >> 2, co = (c & 3) * 8;
        gl2lds16(Ab + (size_t)row * K + k0 + co, &As[c * 8]);
      } else {
        int c2 = c - ACH;
        int row = c2 >> 2, co = (c2 & 3) * 8;
        gl2lds16(Bb + (size_t)row * K + k0 + co, &Bs[c2 * 8]);
      }
    }
    __syncthreads();
    bf16x8 af[MI], bf[4];
#pragma unroll
    for (int i = 0; i < MI; i++) af[i] = *(const bf16x8*)&As[(wr * (BM / 2) + i * 16 + l15) * 32 + quad * 8];
#pragma unroll
    for (int j = 0; j < 4; j++) bf[j] = *(const bf16x8*)&Bs[(wc * 64 + j * 16 + l15) * 32 + quad * 8];
#pragma unroll
    for (int i = 0; i < MI; i++)
#pragma unroll
      for (int j = 0; j < 4; j++)
        acc[i][j] = __builtin_amdgcn_mfma_f32_16x16x32_bf16(af[i], bf[j], acc[i][j], 0, 0, 0);
    __syncthreads();
  }

  float* Cb = C + (size_t)blockIdx.y * BM * N + (size_t)blockIdx.x * 128;
#pragma unroll
  for (int i = 0; i < MI; i++) {
    int rbase = wr * (BM / 2) + i * 16 + quad * 4;
#pragma unroll
    for (int j = 0; j < 4; j++) {
      int col = wc * 64 + j * 16 + l15;
#pragma unroll
      for (int r = 0; r < 4; r++) Cb[(size_t)(rbase + r) * N + col] = acc[i][j][r];
    }
  }
}

// ---------------- RMSNorm + RoPE + cast (one block per token) ----------------
__global__ void norm_rope(const float* __restrict__ qkv, const int* __restrict__ pos,
                          const float* __restrict__ qw, const float* __restrict__ kw,
                          u16* __restrict__ qB, u16* __restrict__ kB, u16* __restrict__ vB) {
  const int t = blockIdx.x;
  const int wave = threadIdx.x >> 6, l = threadIdx.x & 63;
  const float* row = qkv + (size_t)t * QKVW;

  const float p = (float)pos[t];
  const float fr = p * exp2f(-(float)l * 0.20762050593046014f);
  float sn, cs;
  sincosf(fr, &sn, &cs);

  for (int slot = wave; slot < 40; slot += 4) {
    if (slot < 36) {
      const int   base = (slot < 32) ? slot * 128 : 4096 + (slot - 32) * 128;
      const float* w   = (slot < 32) ? qw : kw;
      float x1 = row[base + l], x2 = row[base + 64 + l];
      float ss = x1 * x1 + x2 * x2;
#pragma unroll
      for (int off = 32; off; off >>= 1) ss += __shfl_xor(ss, off);
      float rs = rsqrtf(ss * (1.f / 128.f) + 1e-6f);
      float n1 = x1 * rs * w[l], n2 = x2 * rs * w[64 + l];
      float o1 = n1 * cs - n2 * sn;
      float o2 = n2 * cs + n1 * sn;
      if (slot < 32) {
        o1 *= 0.08838834764831845f;   // fold 1/sqrt(HD) into q
        o2 *= 0.08838834764831845f;
        qB[(size_t)t * QSZ + slot * 128 + l]      = f2bf(o1);
        qB[(size_t)t * QSZ + slot * 128 + 64 + l] = f2bf(o2);
      } else {
        kB[(size_t)t * KVSZ + (slot - 32) * 128 + l]      = f2bf(o1);
        kB[(size_t)t * KVSZ + (slot - 32) * 128 + 64 + l] = f2bf(o2);
      }
    } else {
      int vh = slot - 36;
      float x1 = row[4608 + vh * 128 + l];
      float x2 = row[4608 + vh * 128 + 64 + l];
      vB[(size_t)t * KVSZ + vh * 128 + l]      = f2bf(x1);
      vB[(size_t)t * KVSZ + vh * 128 + 64 + l] = f2bf(x2);
    }
  }
}

// ---------------- V transpose: vB[t][kvh*128+d] -> vT[kvh*128+d][t] ---------
__global__ void transpose_v(const u16* __restrict__ vB, u16* __restrict__ vT) {
  const int vh = blockIdx.y, tb = blockIdx.x;
  const int d0 = threadIdx.x >> 4;          // + s*16
  const int tc = (threadIdx.x & 15) * 8;
#pragma unroll
  for (int s = 0; s < 8; s++) {
    int dd = d0 + s * 16;
    uint4 v; u16* pv = (u16*)&v;
#pragma unroll
    for (int j = 0; j < 8; j++)
      pv[j] = vB[(size_t)(tb * 128 + tc + j) * KVSZ + vh * 128 + dd];
    *(uint4*)&vT[((size_t)vh * 128 + dd) * T_TOK + tb * 128 + tc] = v;
  }
}

// ---------------- flash attention (causal, GQA 8:1) -------------------------
// Rework for occupancy + causal balance:
//  - 64-row q-strips: grid 1024 blocks x 256 threads (4 waves); per-wave
//    geometry unchanged (16 q-rows x 64-key tiles, verified swizzles kept).
//  - single-buffered K/V with reg-staged prefetch issued right after the
//    first barrier (loads fly over QK^T/softmax/PV): LDS 16K+16K+8K = 40 KB
//    -> 4 blocks/CU, 16 waves/CU SUSTAINED (old: 80 KB, 2 blocks/CU decaying
//    to 1 as light causal blocks retired early -> measured 27% occupancy).
//  - LPT slot mapping: with all 1024 blocks resident and round-robin
//    dispatch, CU c gets blocks {b, b+256, b+512, b+768}; slot=b>>8 picks
//    strip costs {32-g, 1+g, 24-g, 9+g} = 66 tile-units on EVERY CU.
//  - only tile kt==p touches the diagonal -> mask once per strip.
//  - defer-max (THR=8): skip O-rescale when row max didn't grow.
__launch_bounds__(256, 4)
__global__ void attn_fa(const u16* __restrict__ qB, const u16* __restrict__ kB,
                        const u16* __restrict__ vT, u16* __restrict__ oB) {
  const int b    = blockIdx.x;
  const int slot = b >> 8, k8 = b & 255;
  const int h    = k8 & 31, g = k8 >> 5;          // g in 0..7
  int p;                                           // q-strip index, 0..31
  if      (slot == 0) p = 31 - g;
  else if (slot == 1) p = g;
  else if (slot == 2) p = 23 - g;
  else                p = 8 + g;
  const int kvh = h >> 3;

  __shared__ __align__(16) u16 Kb[64 * 16 * 8];    // [key][d], swizzled, 16 KB
  __shared__ __align__(16) u16 Vb[128 * 8 * 8];    // [d][key], swizzled, 16 KB
  __shared__ __align__(16) u16 Pb[64 * 8 * 8];     // [row][key], swizzled, 8 KB

  const int tid  = threadIdx.x;
  const int wave = tid >> 6, lane = tid & 63;
  const int l15  = lane & 15, quad = lane >> 4;

  // staging geometry (256 threads): K rows krow+s*16, V rows vrow+s*32
  const int krow = tid >> 4, kmc = tid & 15;
  const int vrow = tid >> 3, vmc = tid & 7;

  bf16x8 qf[4];
#pragma unroll
  for (int ds = 0; ds < 4; ds++)
    qf[ds] = *(const bf16x8*)(qB + (size_t)(p * 64 + wave * 16 + l15) * QSZ
                                 + h * 128 + ds * 32 + quad * 8);

  f32x4 o[8];
#pragma unroll
  for (int ni = 0; ni < 8; ni++) o[ni] = (f32x4){0.f, 0.f, 0.f, 0.f};
  float mrow[4], lrow[4];
#pragma unroll
  for (int r = 0; r < 4; r++) { mrow[r] = -3.0e38f; lrow[r] = 0.f; }

  const int nt = p + 1;                             // 64-key tiles

  uint4 kreg[4], vreg[4];
#pragma unroll
  for (int s = 0; s < 4; s++) {                     // preload tile 0
    kreg[s] = *(const uint4*)(kB + (size_t)(krow + s * 16) * KVSZ + kvh * 128 + kmc * 8);
    vreg[s] = *(const uint4*)(vT + ((size_t)kvh * 128 + vrow + s * 32) * T_TOK + vmc * 8);
  }

  for (int kt = 0; kt < nt; kt++) {
    // 1) staged regs -> swizzled LDS (single buffer)
#pragma unroll
    for (int s = 0; s < 4; s++) {
      int r  = krow + s * 16;
      *(uint4*)&Kb[(r * 16 + (kmc ^ (r & 15))) * 8] = kreg[s];
      int rv = vrow + s * 32;
      *(uint4*)&Vb[(rv * 8 + (vmc ^ (rv & 7))) * 8] = vreg[s];
    }
    // 2) barrier: tile visible to all waves
    __syncthreads();
    // 3) issue next tile's loads now; they fly over this tile's compute
    const int kn = (kt + 1 < nt) ? kt + 1 : kt;
#pragma unroll
    for (int s = 0; s < 4; s++) {
      kreg[s] = *(const uint4*)(kB + (size_t)(kn * 64 + krow + s * 16) * KVSZ + kvh * 128 + kmc * 8);
      vreg[s] = *(const uint4*)(vT + ((size_t)kvh * 128 + vrow + s * 32) * T_TOK + kn * 64 + vmc * 8);
    }

    // 4) S = Q K^T (16 rows x 64 keys per wave)
    f32x4 sc[4];
#pragma unroll
    for (int ni = 0; ni < 4; ni++) sc[ni] = (f32x4){0.f, 0.f, 0.f, 0.f};
#pragma unroll
    for (int ds = 0; ds < 4; ds++) {
#pragma unroll
      for (int ni = 0; ni < 4; ni++) {
        bf16x8 kf = *(const bf16x8*)&Kb[((ni * 16 + l15) * 16 + ((ds * 4 + quad) ^ l15)) * 8];
        sc[ni] = __builtin_amdgcn_mfma_f32_16x16x32_bf16(qf[ds], kf, sc[ni], 0, 0, 0);
      }
    }

    if (kt == p) {  // only the last tile intersects the diagonal
#pragma unroll
      for (int ni = 0; ni < 4; ni++)
#pragma unroll
        for (int r = 0; r < 4; r++) {
          int key = kt * 64 + ni * 16 + l15;
          int rw  = p * 64 + wave * 16 + quad * 4 + r;
          if (key > rw) sc[ni][r] = -1.0e30f;
        }
    }

    // online softmax (stats per 16-lane row-group), defer-max THR=8
#pragma unroll
    for (int r = 0; r < 4; r++) {
      float mx = sc[0][r];
#pragma unroll
      for (int ni = 1; ni < 4; ni++) mx = fmaxf(mx, sc[ni][r]);
#pragma unroll
      for (int off = 1; off < 16; off <<= 1) mx = fmaxf(mx, __shfl_xor(mx, off));
      if (!__all(mx <= mrow[r] + 8.f)) {
        float mn = fmaxf(mrow[r], mx);
        float al = __expf(mrow[r] - mn);
        mrow[r]  = mn;
        lrow[r] *= al;
#pragma unroll
        for (int ni = 0; ni < 8; ni++) o[ni][r] *= al;
      }
      float rs = 0.f;
#pragma unroll
      for (int ni = 0; ni < 4; ni++) {
        float pv = __expf(sc[ni][r] - mrow[r]);
        sc[ni][r] = pv;
        rs += pv;
      }
#pragma unroll
      for (int off = 1; off < 16; off <<= 1) rs += __shfl_xor(rs, off);
      lrow[r] += rs;
    }

    // P (own 16-row strip) -> swizzled Pb; strip-private => no barrier
#pragma unroll
    for (int ni = 0; ni < 4; ni++)
#pragma unroll
      for (int r = 0; r < 4; r++) {
        int row = wave * 16 + quad * 4 + r;
        Pb[(row * 8 + ((ni * 2 + (l15 >> 3)) ^ (row & 7))) * 8 + (l15 & 7)] =
            f2bf(sc[ni][r]);
      }

    // O += P V  (A = own P strip, B = V^T tile)
#pragma unroll
    for (int ks = 0; ks < 2; ks++) {
      bf16x8 pf = *(const bf16x8*)&Pb[((wave * 16 + l15) * 8 + ((ks * 4 + quad) ^ (l15 & 7))) * 8];
#pragma unroll
      for (int ni = 0; ni < 8; ni++) {
        bf16x8 vf = *(const bf16x8*)&Vb[((ni * 16 + l15) * 8 + ((ks * 4 + quad) ^ (l15 & 7))) * 8];
        o[ni] = __builtin_amdgcn_mfma_f32_16x16x32_bf16(pf, vf, o[ni], 0, 0, 0);
      }
    }
    // 5) all waves done reading LDS before next tile's staging overwrites it
    __syncthreads();
  }

  // epilogue: O / l -> bf16
#pragma unroll
  for (int ni = 0; ni < 8; ni++)
#pragma unroll
    for (int r = 0; r < 4; r++) {
      int t = p * 64 + wave * 16 + quad * 4 + r;
      float val = o[ni][r] / lrow[r];
      oB[(size_t)t * QSZ + h * 128 + ni * 16 + l15] = f2bf(val);
    }
}

// ---------------- launch ----------------
extern "C" void kernel_launch(void* const* d_in, const int* in_sizes, int n_in,
                              void* d_out, int out_size, void* d_ws, size_t ws_size,
                              hipStream_t stream) {
  const int*   positions = (const int*)d_in[0];
  const float* hidden    = (const float*)d_in[1];
  const float* w_qkv     = (const float*)d_in[2];
  const float* w_o       = (const float*)d_in[3];
  const float* qw        = (const float*)d_in[4];
  const float* kw        = (const float*)d_in[5];
  float* out = (float*)d_out;
  char*  ws  = (char*)d_ws;

  u16* hiddenB = (u16*)ws;
  u16* wqkvB   = hiddenB + (size_t)HID * HID;
  u16* woB     = wqkvB + (size_t)QKVW * HID;
  size_t off1  = ((size_t)HID * HID + (size_t)QKVW * HID + (size_t)HID * QSZ) * 2;
  float* qkvF  = (float*)(ws + off1);
  u16*   attnB = (u16*)(ws + off1);                          // alias (dead qkvF)
  size_t off2  = off1 + (size_t)T_TOK * QKVW * 4;
  u16* qBuf = (u16*)(ws + off2);
  size_t off3  = off2 + (size_t)T_TOK * QSZ * 2;
  u16* kBuf = (u16*)(ws + off3);
  size_t off4  = off3 + (size_t)T_TOK * KVSZ * 2;
  u16* vTb  = (u16*)(ws + off4);
  size_t off5  = off4 + (size_t)T_TOK * KVSZ * 2;
  u16* vBuf = (u16*)(ws + off5);

  const int n0 = HID * HID / 4, n1 = QKVW * HID / 4, n2 = HID * QSZ / 4;
  cvt3_f32_bf16<<<(n0 + n1 + n2 + 255) / 256, 256, 0, stream>>>(
      hidden, hiddenB, n0, w_qkv, wqkvB, n1, w_o, woB, n2);

  gemm_nt<128><<<dim3(QKVW / 128, T_TOK / 128), 256, 0, stream>>>(hiddenB, wqkvB, qkvF, T_TOK, QKVW, HID);

  norm_rope<<<T_TOK, 256, 0, stream>>>(qkvF, positions, qw, kw, qBuf, kBuf, vBuf);

  transpose_v<<<dim3(T_TOK / 128, NKV), 256, 0, stream>>>(vBuf, vTb);

  attn_fa<<<dim3(1024), 256, 0, stream>>>(qBuf, kBuf, vTb, attnB);

  gemm_nt<64><<<dim3(HID / 128, T_TOK / 64), 256, 0, stream>>>(attnB, woB, out, T_TOK, HID, QSZ);
}

// Round 2
// 366.538 us; speedup vs baseline: 1.3617x; 1.3617x over previous
//
#include <hip/hip_runtime.h>

// ---- problem constants ----
#define T_TOK   2048
#define HID     2048
#define NHEADS  32
#define NKV     4
#define HD      128
#define QSZ     4096          // 32*128
#define KVSZ    512           // 4*128
#define QKVW    5120          // QSZ + 2*KVSZ

typedef unsigned short u16;
typedef __bf16 bf16x8 __attribute__((ext_vector_type(8)));
typedef float  f32x4  __attribute__((ext_vector_type(4)));

__device__ __forceinline__ u16 f2bf(float f) {
  unsigned int u = __float_as_uint(f);
  u += 0x7fffu + ((u >> 16) & 1u);   // RNE
  return (u16)(u >> 16);
}

// async 16B global -> LDS (wave-uniform base + lane*16 semantics)
__device__ __forceinline__ void gl2lds16(const void* g, void* l) {
  __builtin_amdgcn_global_load_lds(
      (const __attribute__((address_space(1))) unsigned int*)g,
      (__attribute__((address_space(3))) unsigned int*)l, 16, 0, 0);
}

// ---------------- fused fp32 -> bf16 convert (3 arrays, one launch) ---------
__global__ void cvt3_f32_bf16(const float* __restrict__ in0, u16* __restrict__ o0, int n0,
                              const float* __restrict__ in1, u16* __restrict__ o1, int n1,
                              const float* __restrict__ in2, u16* __restrict__ o2, int n2) {
  int i = blockIdx.x * blockDim.x + threadIdx.x;
  const float* in; u16* out;
  if (i < n0)            { in = in0; out = o0; }
  else if (i < n0 + n1)  { in = in1; out = o1; i -= n0; }
  else if (i < n0+n1+n2) { in = in2; out = o2; i -= n0 + n1; }
  else return;
  float4 v = ((const float4*)in)[i];
  ushort4 o;
  o.x = f2bf(v.x); o.y = f2bf(v.y); o.z = f2bf(v.z); o.w = f2bf(v.w);
  ((ushort4*)out)[i] = o;
}

// ---------------- NT GEMM: C[m][n] = sum_k A[m][k]*B[n][k] ----------------
template<int BM>
__launch_bounds__(256, 2)
__global__ void gemm_nt(const u16* __restrict__ A, const u16* __restrict__ B,
                        float* __restrict__ C, int M, int N, int K) {
  constexpr int MI = BM / 32;          // m-tiles per wave
  __shared__ __align__(16) u16 As[BM * 32];
  __shared__ __align__(16) u16 Bs[128 * 32];
  const int tid  = threadIdx.x;
  const int wave = tid >> 6, lane = tid & 63;
  const int l15  = lane & 15, quad = lane >> 4;
  const int wr   = wave >> 1, wc = wave & 1;

  const u16* Ab = A + (size_t)blockIdx.y * BM * K;
  const u16* Bb = B + (size_t)blockIdx.x * 128 * K;

  f32x4 acc[MI][4];
#pragma unroll
  for (int i = 0; i < MI; i++)
#pragma unroll
    for (int j = 0; j < 4; j++) acc[i][j] = (f32x4){0.f, 0.f, 0.f, 0.f};

  constexpr int ACH = BM * 32 / 8;     // 16B chunks in A tile
  for (int k0 = 0; k0 < K; k0 += 32) {
#pragma unroll
    for (int s = 0; s < (ACH + 512) / 256; s++) {
      int c = tid + s * 256;
      if (c < ACH) {
        int row = c >> 2, co = (c & 3) * 8;
        gl2lds16(Ab + (size_t)row * K + k0 + co, &As[c * 8]);
      } else {
        int c2 = c - ACH;
        int row = c2 >> 2, co = (c2 & 3) * 8;
        gl2lds16(Bb + (size_t)row * K + k0 + co, &Bs[c2 * 8]);
      }
    }
    __syncthreads();
    bf16x8 af[MI], bf[4];
#pragma unroll
    for (int i = 0; i < MI; i++) af[i] = *(const bf16x8*)&As[(wr * (BM / 2) + i * 16 + l15) * 32 + quad * 8];
#pragma unroll
    for (int j = 0; j < 4; j++) bf[j] = *(const bf16x8*)&Bs[(wc * 64 + j * 16 + l15) * 32 + quad * 8];
#pragma unroll
    for (int i = 0; i < MI; i++)
#pragma unroll
      for (int j = 0; j < 4; j++)
        acc[i][j] = __builtin_amdgcn_mfma_f32_16x16x32_bf16(af[i], bf[j], acc[i][j], 0, 0, 0);
    __syncthreads();
  }

  float* Cb = C + (size_t)blockIdx.y * BM * N + (size_t)blockIdx.x * 128;
#pragma unroll
  for (int i = 0; i < MI; i++) {
    int rbase = wr * (BM / 2) + i * 16 + quad * 4;
#pragma unroll
    for (int j = 0; j < 4; j++) {
      int col = wc * 64 + j * 16 + l15;
#pragma unroll
      for (int r = 0; r < 4; r++) Cb[(size_t)(rbase + r) * N + col] = acc[i][j][r];
    }
  }
}

// ---------------- RMSNorm + RoPE + cast (one block per token) ----------------
__global__ void norm_rope(const float* __restrict__ qkv, const int* __restrict__ pos,
                          const float* __restrict__ qw, const float* __restrict__ kw,
                          u16* __restrict__ qB, u16* __restrict__ kB, u16* __restrict__ vB) {
  const int t = blockIdx.x;
  const int wave = threadIdx.x >> 6, l = threadIdx.x & 63;
  const float* row = qkv + (size_t)t * QKVW;

  const float p = (float)pos[t];
  const float fr = p * exp2f(-(float)l * 0.20762050593046014f);
  float sn, cs;
  sincosf(fr, &sn, &cs);

  for (int slot = wave; slot < 40; slot += 4) {
    if (slot < 36) {
      const int   base = (slot < 32) ? slot * 128 : 4096 + (slot - 32) * 128;
      const float* w   = (slot < 32) ? qw : kw;
      float x1 = row[base + l], x2 = row[base + 64 + l];
      float ss = x1 * x1 + x2 * x2;
#pragma unroll
      for (int off = 32; off; off >>= 1) ss += __shfl_xor(ss, off);
      float rs = rsqrtf(ss * (1.f / 128.f) + 1e-6f);
      float n1 = x1 * rs * w[l], n2 = x2 * rs * w[64 + l];
      float o1 = n1 * cs - n2 * sn;
      float o2 = n2 * cs + n1 * sn;
      if (slot < 32) {
        o1 *= 0.08838834764831845f;   // fold 1/sqrt(HD) into q
        o2 *= 0.08838834764831845f;
        qB[(size_t)t * QSZ + slot * 128 + l]      = f2bf(o1);
        qB[(size_t)t * QSZ + slot * 128 + 64 + l] = f2bf(o2);
      } else {
        kB[(size_t)t * KVSZ + (slot - 32) * 128 + l]      = f2bf(o1);
        kB[(size_t)t * KVSZ + (slot - 32) * 128 + 64 + l] = f2bf(o2);
      }
    } else {
      int vh = slot - 36;
      float x1 = row[4608 + vh * 128 + l];
      float x2 = row[4608 + vh * 128 + 64 + l];
      vB[(size_t)t * KVSZ + vh * 128 + l]      = f2bf(x1);
      vB[(size_t)t * KVSZ + vh * 128 + 64 + l] = f2bf(x2);
    }
  }
}

// ---------------- V transpose: vB[t][kvh*128+d] -> vT[kvh*128+d][t] ---------
__global__ void transpose_v(const u16* __restrict__ vB, u16* __restrict__ vT) {
  const int vh = blockIdx.y, tb = blockIdx.x;
  const int d0 = threadIdx.x >> 4;          // + s*16
  const int tc = (threadIdx.x & 15) * 8;
#pragma unroll
  for (int s = 0; s < 8; s++) {
    int dd = d0 + s * 16;
    uint4 v; u16* pv = (u16*)&v;
#pragma unroll
    for (int j = 0; j < 8; j++)
      pv[j] = vB[(size_t)(tb * 128 + tc + j) * KVSZ + vh * 128 + dd];
    *(uint4*)&vT[((size_t)vh * 128 + dd) * T_TOK + tb * 128 + tc] = v;
  }
}

// ---------------- flash attention (causal, GQA 8:1) -------------------------
// Round-0 geometry (512 thr / 8 waves, 128-row q-strips, 64-key tiles,
// double-buffered K/V, x-reversal pairing -> uniform 34 tile-units/CU), with
// the staging registers ELIMINATED: K/V tiles are DMA'd via global_load_lds
// with PRE-SWIZZLED global source columns (rule #21: linear LDS dest, the
// source permutation equals the read-side XOR involution). This cuts ~32
// VGPRs of demand -> fits the 128-reg cap of launch_bounds(512,4) with
// headroom -> no scratch spill (r1's 525 MB WRITE_SIZE regression).
// One __syncthreads per tile: its implicit vmcnt(0) drain completes tile
// kt's DMA; tile kt+1's DMA is issued right after the barrier into buf^1
// (safe: buf^1's readers finished at compute(kt-1), before this barrier)
// and flies over a full tile of compute. Defer-max (THR=8, r1-verified)
// and s_setprio around MFMA clusters (T5, +4-7% attn) retained.
__launch_bounds__(512, 4)
__global__ void attn_fa(const u16* __restrict__ qB, const u16* __restrict__ kB,
                        const u16* __restrict__ vT, u16* __restrict__ oB) {
  const int qb  = (blockIdx.y < 16) ? (15 - (int)blockIdx.x) : (int)blockIdx.x;
  const int h   = blockIdx.y;
  const int kvh = h >> 3;
  __shared__ __align__(16) u16 Kb[2][64 * 16 * 8];   // [key][d], swizzled, 16 KB each
  __shared__ __align__(16) u16 Vb[2][128 * 8 * 8];   // [d][key], swizzled, 16 KB each
  __shared__ __align__(16) u16 Pb[128 * 8 * 8];      // [row][key], swizzled, 16 KB

  const int tid  = threadIdx.x;
  const int wave = tid >> 6, lane = tid & 63;
  const int l15  = lane & 15, quad = lane >> 4;

  // DMA one 64-key tile (K: [key][d] 16KB, V^T: [d][key] 16KB) into buf.
  // Linear LDS chunk c receives global chunk (c&mask)^(row&mask): the same
  // XOR involution the reads use, so read-side swizzles are unchanged.
  auto stage = [&](int kt, int buf) {
#pragma unroll
    for (int s = 0; s < 2; s++) {
      int c = tid + s * 512;                 // 16B chunk id, 0..1023
      int r = c >> 4;                        // key row 0..63
      gl2lds16(kB + (size_t)(kt * 64 + r) * KVSZ + kvh * 128 + ((c & 15) ^ (r & 15)) * 8,
               &Kb[buf][c * 8]);
    }
#pragma unroll
    for (int s = 0; s < 2; s++) {
      int c = tid + s * 512;                 // 16B chunk id, 0..1023
      int rv = c >> 3;                       // d row 0..127
      gl2lds16(vT + ((size_t)kvh * 128 + rv) * T_TOK + kt * 64 + ((c & 7) ^ (rv & 7)) * 8,
               &Vb[buf][c * 8]);
    }
  };

  bf16x8 qf[4];
#pragma unroll
  for (int ds = 0; ds < 4; ds++)
    qf[ds] = *(const bf16x8*)(qB + (size_t)(qb * 128 + wave * 16 + l15) * QSZ
                                 + h * 128 + ds * 32 + quad * 8);

  f32x4 o[8];
#pragma unroll
  for (int ni = 0; ni < 8; ni++) o[ni] = (f32x4){0.f, 0.f, 0.f, 0.f};
  float mrow[4], lrow[4];
#pragma unroll
  for (int r = 0; r < 4; r++) { mrow[r] = -3.0e38f; lrow[r] = 0.f; }

  const int nt = 2 * qb + 2;                   // 64-key tiles

  stage(0, 0);                                 // prologue DMA, tile 0 -> buf 0

  for (int kt = 0; kt < nt; kt++) {
    const int cur = kt & 1;
    // barrier: implicit vmcnt(0) drains tile kt's DMA for THIS wave, then
    // s_barrier makes every wave's DMA visible; also fences buf^1 readers.
    __syncthreads();
    // issue next tile's DMA now; it overlaps this whole tile's compute
    if (kt + 1 < nt) stage(kt + 1, cur ^ 1);

    // S = Q K^T (16 rows x 64 keys per wave)
    f32x4 sc[4];
#pragma unroll
    for (int ni = 0; ni < 4; ni++) sc[ni] = (f32x4){0.f, 0.f, 0.f, 0.f};
    __builtin_amdgcn_s_setprio(1);
#pragma unroll
    for (int ds = 0; ds < 4; ds++) {
#pragma unroll
      for (int ni = 0; ni < 4; ni++) {
        bf16x8 kf = *(const bf16x8*)&Kb[cur][((ni * 16 + l15) * 16 + ((ds * 4 + quad) ^ l15)) * 8];
        sc[ni] = __builtin_amdgcn_mfma_f32_16x16x32_bf16(qf[ds], kf, sc[ni], 0, 0, 0);
      }
    }
    __builtin_amdgcn_s_setprio(0);

    if (kt >= 2 * qb) {  // tiles intersecting the diagonal
#pragma unroll
      for (int ni = 0; ni < 4; ni++)
#pragma unroll
        for (int r = 0; r < 4; r++) {
          int key = kt * 64 + ni * 16 + l15;
          int rw  = qb * 128 + wave * 16 + quad * 4 + r;
          if (key > rw) sc[ni][r] = -1.0e30f;
        }
    }

    // online softmax (stats per 16-lane row-group), defer-max THR=8
#pragma unroll
    for (int r = 0; r < 4; r++) {
      float mx = sc[0][r];
#pragma unroll
      for (int ni = 1; ni < 4; ni++) mx = fmaxf(mx, sc[ni][r]);
#pragma unroll
      for (int off = 1; off < 16; off <<= 1) mx = fmaxf(mx, __shfl_xor(mx, off));
      if (!__all(mx <= mrow[r] + 8.f)) {
        float mn = fmaxf(mrow[r], mx);
        float al = __expf(mrow[r] - mn);
        mrow[r]  = mn;
        lrow[r] *= al;
#pragma unroll
        for (int ni = 0; ni < 8; ni++) o[ni][r] *= al;
      }
      float rs = 0.f;
#pragma unroll
      for (int ni = 0; ni < 4; ni++) {
        float pv = __expf(sc[ni][r] - mrow[r]);
        sc[ni][r] = pv;
        rs += pv;
      }
#pragma unroll
      for (int off = 1; off < 16; off <<= 1) rs += __shfl_xor(rs, off);
      lrow[r] += rs;
    }

    // P (own 16-row strip) -> swizzled Pb; strip-private => no barrier
#pragma unroll
    for (int ni = 0; ni < 4; ni++)
#pragma unroll
      for (int r = 0; r < 4; r++) {
        int row = wave * 16 + quad * 4 + r;
        Pb[(row * 8 + ((ni * 2 + (l15 >> 3)) ^ (row & 7))) * 8 + (l15 & 7)] =
            f2bf(sc[ni][r]);
      }

    // O += P V  (A = own P strip, B = V^T tile)
    __builtin_amdgcn_s_setprio(1);
#pragma unroll
    for (int ks = 0; ks < 2; ks++) {
      bf16x8 pf = *(const bf16x8*)&Pb[((wave * 16 + l15) * 8 + ((ks * 4 + quad) ^ (l15 & 7))) * 8];
#pragma unroll
      for (int ni = 0; ni < 8; ni++) {
        bf16x8 vf = *(const bf16x8*)&Vb[cur][((ni * 16 + l15) * 8 + ((ks * 4 + quad) ^ (l15 & 7))) * 8];
        o[ni] = __builtin_amdgcn_mfma_f32_16x16x32_bf16(pf, vf, o[ni], 0, 0, 0);
      }
    }
    __builtin_amdgcn_s_setprio(0);
  }

  // epilogue: O / l -> bf16
#pragma unroll
  for (int ni = 0; ni < 8; ni++)
#pragma unroll
    for (int r = 0; r < 4; r++) {
      int t = qb * 128 + wave * 16 + quad * 4 + r;
      float val = o[ni][r] / lrow[r];
      oB[(size_t)t * QSZ + h * 128 + ni * 16 + l15] = f2bf(val);
    }
}

// ---------------- launch ----------------
extern "C" void kernel_launch(void* const* d_in, const int* in_sizes, int n_in,
                              void* d_out, int out_size, void* d_ws, size_t ws_size,
                              hipStream_t stream) {
  const int*   positions = (const int*)d_in[0];
  const float* hidden    = (const float*)d_in[1];
  const float* w_qkv     = (const float*)d_in[2];
  const float* w_o       = (const float*)d_in[3];
  const float* qw        = (const float*)d_in[4];
  const float* kw        = (const float*)d_in[5];
  float* out = (float*)d_out;
  char*  ws  = (char*)d_ws;

  u16* hiddenB = (u16*)ws;
  u16* wqkvB   = hiddenB + (size_t)HID * HID;
  u16* woB     = wqkvB + (size_t)QKVW * HID;
  size_t off1  = ((size_t)HID * HID + (size_t)QKVW * HID + (size_t)HID * QSZ) * 2;
  float* qkvF  = (float*)(ws + off1);
  u16*   attnB = (u16*)(ws + off1);                          // alias (dead qkvF)
  size_t off2  = off1 + (size_t)T_TOK * QKVW * 4;
  u16* qBuf = (u16*)(ws + off2);
  size_t off3  = off2 + (size_t)T_TOK * QSZ * 2;
  u16* kBuf = (u16*)(ws + off3);
  size_t off4  = off3 + (size_t)T_TOK * KVSZ * 2;
  u16* vTb  = (u16*)(ws + off4);
  size_t off5  = off4 + (size_t)T_TOK * KVSZ * 2;
  u16* vBuf = (u16*)(ws + off5);

  const int n0 = HID * HID / 4, n1 = QKVW * HID / 4, n2 = HID * QSZ / 4;
  cvt3_f32_bf16<<<(n0 + n1 + n2 + 255) / 256, 256, 0, stream>>>(
      hidden, hiddenB, n0, w_qkv, wqkvB, n1, w_o, woB, n2);

  gemm_nt<128><<<dim3(QKVW / 128, T_TOK / 128), 256, 0, stream>>>(hiddenB, wqkvB, qkvF, T_TOK, QKVW, HID);

  norm_rope<<<T_TOK, 256, 0, stream>>>(qkvF, positions, qw, kw, qBuf, kBuf, vBuf);

  transpose_v<<<dim3(T_TOK / 128, NKV), 256, 0, stream>>>(vBuf, vTb);

  attn_fa<<<dim3(T_TOK / 128, NHEADS), 512, 0, stream>>>(qBuf, kBuf, vTb, attnB);

  gemm_nt<64><<<dim3(HID / 128, T_TOK / 64), 256, 0, stream>>>(attnB, woB, out, T_TOK, HID, QSZ);
}

// Round 3
// 359.878 us; speedup vs baseline: 1.3869x; 1.0185x over previous
//
#include <hip/hip_runtime.h>

// ---- problem constants ----
#define T_TOK   2048
#define HID     2048
#define NHEADS  32
#define NKV     4
#define HD      128
#define QSZ     4096          // 32*128
#define KVSZ    512           // 4*128
#define QKVW    5120          // QSZ + 2*KVSZ

typedef unsigned short u16;
typedef __bf16 bf16x8 __attribute__((ext_vector_type(8)));
typedef float  f32x4  __attribute__((ext_vector_type(4)));

__device__ __forceinline__ u16 f2bf(float f) {
  unsigned int u = __float_as_uint(f);
  u += 0x7fffu + ((u >> 16) & 1u);   // RNE
  return (u16)(u >> 16);
}

// async 16B global -> LDS (wave-uniform base + lane*16 semantics)
__device__ __forceinline__ void gl2lds16(const void* g, void* l) {
  __builtin_amdgcn_global_load_lds(
      (const __attribute__((address_space(1))) unsigned int*)g,
      (__attribute__((address_space(3))) unsigned int*)l, 16, 0, 0);
}

// 16-lane-group reductions via DPP row_ror (VALU latency, ~4-8 cyc/step,
// vs __shfl_xor's LDS-pipe ds_swizzle at ~25-30 cyc/step). DPP rows are
// exactly our 16-lane groups (lanes 0-15, 16-31, 32-47, 48-63).
template<int N>
__device__ __forceinline__ float rotmax(float x) {
  int t = __builtin_amdgcn_mov_dpp(__float_as_int(x), 0x120 | N, 0xf, 0xf, true);
  return fmaxf(x, __int_as_float(t));
}
template<int N>
__device__ __forceinline__ float rotadd(float x) {
  int t = __builtin_amdgcn_mov_dpp(__float_as_int(x), 0x120 | N, 0xf, 0xf, true);
  return x + __int_as_float(t);
}

// ---------------- fused fp32 -> bf16 convert (3 arrays, one launch) ---------
__global__ void cvt3_f32_bf16(const float* __restrict__ in0, u16* __restrict__ o0, int n0,
                              const float* __restrict__ in1, u16* __restrict__ o1, int n1,
                              const float* __restrict__ in2, u16* __restrict__ o2, int n2) {
  int i = blockIdx.x * blockDim.x + threadIdx.x;
  const float* in; u16* out;
  if (i < n0)            { in = in0; out = o0; }
  else if (i < n0 + n1)  { in = in1; out = o1; i -= n0; }
  else if (i < n0+n1+n2) { in = in2; out = o2; i -= n0 + n1; }
  else return;
  float4 v = ((const float4*)in)[i];
  ushort4 o;
  o.x = f2bf(v.x); o.y = f2bf(v.y); o.z = f2bf(v.z); o.w = f2bf(v.w);
  ((ushort4*)out)[i] = o;
}

// ---------------- NT GEMM: C[m][n] = sum_k A[m][k]*B[n][k] ----------------
// XCD-aware bijective block swizzle (T1): both launches have nwg % 8 == 0
// (640, 512). Consecutive swizzled ids share the A-panel and land on the
// same XCD's L2 (B/A panels are multi-MB and span XCD L2s otherwise).
template<int BM>
__launch_bounds__(256, 2)
__global__ void gemm_nt(const u16* __restrict__ A, const u16* __restrict__ B,
                        float* __restrict__ C, int M, int N, int K) {
  constexpr int MI = BM / 32;          // m-tiles per wave
  __shared__ __align__(16) u16 As[BM * 32];
  __shared__ __align__(16) u16 Bs[128 * 32];
  const int tid  = threadIdx.x;
  const int wave = tid >> 6, lane = tid & 63;
  const int l15  = lane & 15, quad = lane >> 4;
  const int wr   = wave >> 1, wc = wave & 1;

  const int nwg = gridDim.x * gridDim.y;
  int lid = blockIdx.y * gridDim.x + blockIdx.x;
  lid = (lid & 7) * (nwg >> 3) + (lid >> 3);
  const int bx = lid % gridDim.x;
  const int by = lid / gridDim.x;

  const u16* Ab = A + (size_t)by * BM * K;
  const u16* Bb = B + (size_t)bx * 128 * K;

  f32x4 acc[MI][4];
#pragma unroll
  for (int i = 0; i < MI; i++)
#pragma unroll
    for (int j = 0; j < 4; j++) acc[i][j] = (f32x4){0.f, 0.f, 0.f, 0.f};

  constexpr int ACH = BM * 32 / 8;     // 16B chunks in A tile
  for (int k0 = 0; k0 < K; k0 += 32) {
#pragma unroll
    for (int s = 0; s < (ACH + 512) / 256; s++) {
      int c = tid + s * 256;
      if (c < ACH) {
        int row = c >> 2, co = (c & 3) * 8;
        gl2lds16(Ab + (size_t)row * K + k0 + co, &As[c * 8]);
      } else {
        int c2 = c - ACH;
        int row = c2 >> 2, co = (c2 & 3) * 8;
        gl2lds16(Bb + (size_t)row * K + k0 + co, &Bs[c2 * 8]);
      }
    }
    __syncthreads();
    bf16x8 af[MI], bf[4];
#pragma unroll
    for (int i = 0; i < MI; i++) af[i] = *(const bf16x8*)&As[(wr * (BM / 2) + i * 16 + l15) * 32 + quad * 8];
#pragma unroll
    for (int j = 0; j < 4; j++) bf[j] = *(const bf16x8*)&Bs[(wc * 64 + j * 16 + l15) * 32 + quad * 8];
#pragma unroll
    for (int i = 0; i < MI; i++)
#pragma unroll
      for (int j = 0; j < 4; j++)
        acc[i][j] = __builtin_amdgcn_mfma_f32_16x16x32_bf16(af[i], bf[j], acc[i][j], 0, 0, 0);
    __syncthreads();
  }

  float* Cb = C + (size_t)by * BM * N + (size_t)bx * 128;
#pragma unroll
  for (int i = 0; i < MI; i++) {
    int rbase = wr * (BM / 2) + i * 16 + quad * 4;
#pragma unroll
    for (int j = 0; j < 4; j++) {
      int col = wc * 64 + j * 16 + l15;
#pragma unroll
      for (int r = 0; r < 4; r++) Cb[(size_t)(rbase + r) * N + col] = acc[i][j][r];
    }
  }
}

// ---------------- RMSNorm + RoPE + cast (one block per token) ----------------
// q additionally folds log2(e) so attention scores arrive in the exp2 domain
// (softmax then uses raw v_exp_f32 with no per-element log2e multiply).
__global__ void norm_rope(const float* __restrict__ qkv, const int* __restrict__ pos,
                          const float* __restrict__ qw, const float* __restrict__ kw,
                          u16* __restrict__ qB, u16* __restrict__ kB, u16* __restrict__ vB) {
  const int t = blockIdx.x;
  const int wave = threadIdx.x >> 6, l = threadIdx.x & 63;
  const float* row = qkv + (size_t)t * QKVW;

  constexpr float QSC = 0.08838834764831845f * 1.4426950408889634f; // 1/sqrt(HD) * log2(e)

  const float p = (float)pos[t];
  const float fr = p * exp2f(-(float)l * 0.20762050593046014f);
  float sn, cs;
  sincosf(fr, &sn, &cs);

  for (int slot = wave; slot < 40; slot += 4) {
    if (slot < 36) {
      const int   base = (slot < 32) ? slot * 128 : 4096 + (slot - 32) * 128;
      const float* w   = (slot < 32) ? qw : kw;
      float x1 = row[base + l], x2 = row[base + 64 + l];
      float ss = x1 * x1 + x2 * x2;
#pragma unroll
      for (int off = 32; off; off >>= 1) ss += __shfl_xor(ss, off);
      float rs = rsqrtf(ss * (1.f / 128.f) + 1e-6f);
      float n1 = x1 * rs * w[l], n2 = x2 * rs * w[64 + l];
      float o1 = n1 * cs - n2 * sn;
      float o2 = n2 * cs + n1 * sn;
      if (slot < 32) {
        o1 *= QSC;
        o2 *= QSC;
        qB[(size_t)t * QSZ + slot * 128 + l]      = f2bf(o1);
        qB[(size_t)t * QSZ + slot * 128 + 64 + l] = f2bf(o2);
      } else {
        kB[(size_t)t * KVSZ + (slot - 32) * 128 + l]      = f2bf(o1);
        kB[(size_t)t * KVSZ + (slot - 32) * 128 + 64 + l] = f2bf(o2);
      }
    } else {
      int vh = slot - 36;
      float x1 = row[4608 + vh * 128 + l];
      float x2 = row[4608 + vh * 128 + 64 + l];
      vB[(size_t)t * KVSZ + vh * 128 + l]      = f2bf(x1);
      vB[(size_t)t * KVSZ + vh * 128 + 64 + l] = f2bf(x2);
    }
  }
}

// ---------------- V transpose: vB[t][kvh*128+d] -> vT[kvh*128+d][t] ---------
__global__ void transpose_v(const u16* __restrict__ vB, u16* __restrict__ vT) {
  const int vh = blockIdx.y, tb = blockIdx.x;
  const int d0 = threadIdx.x >> 4;          // + s*16
  const int tc = (threadIdx.x & 15) * 8;
#pragma unroll
  for (int s = 0; s < 8; s++) {
    int dd = d0 + s * 16;
    uint4 v; u16* pv = (u16*)&v;
#pragma unroll
    for (int j = 0; j < 8; j++)
      pv[j] = vB[(size_t)(tb * 128 + tc + j) * KVSZ + vh * 128 + dd];
    *(uint4*)&vT[((size_t)vh * 128 + dd) * T_TOK + tb * 128 + tc] = v;
  }
}

// ---------------- flash attention (causal, GQA 8:1) -------------------------
// r2 structure (memory-clean, spill-free): 512 thr / 8 waves, 128-row
// q-strips, 64-key tiles, double-buffered K/V via global_load_lds with
// PRE-SWIZZLED global source (rule #21), one barrier/tile, x-reversal
// pairing (uniform 34 tile-units/CU). r3 adds: DPP rotate-reduce for the
// softmax max/sum (replaces 8 LDS-pipe __shfl_xor per row with VALU-latency
// DPP), exp2-domain softmax (log2e folded into q), epilogue rcp.
__launch_bounds__(512, 4)
__global__ void attn_fa(const u16* __restrict__ qB, const u16* __restrict__ kB,
                        const u16* __restrict__ vT, u16* __restrict__ oB) {
  const int qb  = (blockIdx.y < 16) ? (15 - (int)blockIdx.x) : (int)blockIdx.x;
  const int h   = blockIdx.y;
  const int kvh = h >> 3;
  __shared__ __align__(16) u16 Kb[2][64 * 16 * 8];   // [key][d], swizzled, 16 KB each
  __shared__ __align__(16) u16 Vb[2][128 * 8 * 8];   // [d][key], swizzled, 16 KB each
  __shared__ __align__(16) u16 Pb[128 * 8 * 8];      // [row][key], swizzled, 16 KB

  const int tid  = threadIdx.x;
  const int wave = tid >> 6, lane = tid & 63;
  const int l15  = lane & 15, quad = lane >> 4;

  // DMA one 64-key tile (K: [key][d] 16KB, V^T: [d][key] 16KB) into buf.
  // Linear LDS chunk c receives global chunk (c&mask)^(row&mask): the same
  // XOR involution the reads use, so read-side swizzles are unchanged.
  auto stage = [&](int kt, int buf) {
#pragma unroll
    for (int s = 0; s < 2; s++) {
      int c = tid + s * 512;                 // 16B chunk id, 0..1023
      int r = c >> 4;                        // key row 0..63
      gl2lds16(kB + (size_t)(kt * 64 + r) * KVSZ + kvh * 128 + ((c & 15) ^ (r & 15)) * 8,
               &Kb[buf][c * 8]);
    }
#pragma unroll
    for (int s = 0; s < 2; s++) {
      int c = tid + s * 512;                 // 16B chunk id, 0..1023
      int rv = c >> 3;                       // d row 0..127
      gl2lds16(vT + ((size_t)kvh * 128 + rv) * T_TOK + kt * 64 + ((c & 7) ^ (rv & 7)) * 8,
               &Vb[buf][c * 8]);
    }
  };

  bf16x8 qf[4];
#pragma unroll
  for (int ds = 0; ds < 4; ds++)
    qf[ds] = *(const bf16x8*)(qB + (size_t)(qb * 128 + wave * 16 + l15) * QSZ
                                 + h * 128 + ds * 32 + quad * 8);

  f32x4 o[8];
#pragma unroll
  for (int ni = 0; ni < 8; ni++) o[ni] = (f32x4){0.f, 0.f, 0.f, 0.f};
  float mrow[4], lrow[4];
#pragma unroll
  for (int r = 0; r < 4; r++) { mrow[r] = -3.0e38f; lrow[r] = 0.f; }

  const int nt = 2 * qb + 2;                   // 64-key tiles

  stage(0, 0);                                 // prologue DMA, tile 0 -> buf 0

  for (int kt = 0; kt < nt; kt++) {
    const int cur = kt & 1;
    // barrier: implicit vmcnt(0) drains tile kt's DMA for THIS wave, then
    // s_barrier makes every wave's DMA visible; also fences buf^1 readers.
    __syncthreads();
    // issue next tile's DMA now; it overlaps this whole tile's compute
    if (kt + 1 < nt) stage(kt + 1, cur ^ 1);

    // S = Q K^T (16 rows x 64 keys per wave)
    f32x4 sc[4];
#pragma unroll
    for (int ni = 0; ni < 4; ni++) sc[ni] = (f32x4){0.f, 0.f, 0.f, 0.f};
    __builtin_amdgcn_s_setprio(1);
#pragma unroll
    for (int ds = 0; ds < 4; ds++) {
#pragma unroll
      for (int ni = 0; ni < 4; ni++) {
        bf16x8 kf = *(const bf16x8*)&Kb[cur][((ni * 16 + l15) * 16 + ((ds * 4 + quad) ^ l15)) * 8];
        sc[ni] = __builtin_amdgcn_mfma_f32_16x16x32_bf16(qf[ds], kf, sc[ni], 0, 0, 0);
      }
    }
    __builtin_amdgcn_s_setprio(0);

    if (kt >= 2 * qb) {  // tiles intersecting the diagonal
#pragma unroll
      for (int ni = 0; ni < 4; ni++)
#pragma unroll
        for (int r = 0; r < 4; r++) {
          int key = kt * 64 + ni * 16 + l15;
          int rw  = qb * 128 + wave * 16 + quad * 4 + r;
          if (key > rw) sc[ni][r] = -1.0e30f;
        }
    }

    // online softmax in exp2 domain (stats per 16-lane row-group),
    // defer-max THR=8 (P bounded by 2^8), DPP rotate-reduce.
#pragma unroll
    for (int r = 0; r < 4; r++) {
      float mx = fmaxf(fmaxf(sc[0][r], sc[1][r]), fmaxf(sc[2][r], sc[3][r]));
      mx = rotmax<1>(mx); mx = rotmax<2>(mx); mx = rotmax<4>(mx); mx = rotmax<8>(mx);
      if (!__all(mx <= mrow[r] + 8.f)) {
        float mn = fmaxf(mrow[r], mx);
        float al = exp2f(mrow[r] - mn);
        mrow[r]  = mn;
        lrow[r] *= al;
#pragma unroll
        for (int ni = 0; ni < 8; ni++) o[ni][r] *= al;
      }
      float rs = 0.f;
#pragma unroll
      for (int ni = 0; ni < 4; ni++) {
        float pv = exp2f(sc[ni][r] - mrow[r]);
        sc[ni][r] = pv;
        rs += pv;
      }
      rs = rotadd<1>(rs); rs = rotadd<2>(rs); rs = rotadd<4>(rs); rs = rotadd<8>(rs);
      lrow[r] += rs;
    }

    // P (own 16-row strip) -> swizzled Pb; strip-private => no barrier
#pragma unroll
    for (int ni = 0; ni < 4; ni++)
#pragma unroll
      for (int r = 0; r < 4; r++) {
        int row = wave * 16 + quad * 4 + r;
        Pb[(row * 8 + ((ni * 2 + (l15 >> 3)) ^ (row & 7))) * 8 + (l15 & 7)] =
            f2bf(sc[ni][r]);
      }

    // O += P V  (A = own P strip, B = V^T tile)
    __builtin_amdgcn_s_setprio(1);
#pragma unroll
    for (int ks = 0; ks < 2; ks++) {
      bf16x8 pf = *(const bf16x8*)&Pb[((wave * 16 + l15) * 8 + ((ks * 4 + quad) ^ (l15 & 7))) * 8];
#pragma unroll
      for (int ni = 0; ni < 8; ni++) {
        bf16x8 vf = *(const bf16x8*)&Vb[cur][((ni * 16 + l15) * 8 + ((ks * 4 + quad) ^ (l15 & 7))) * 8];
        o[ni] = __builtin_amdgcn_mfma_f32_16x16x32_bf16(pf, vf, o[ni], 0, 0, 0);
      }
    }
    __builtin_amdgcn_s_setprio(0);
  }

  // epilogue: O * (1/l) -> bf16 (4 divides instead of 32)
#pragma unroll
  for (int r = 0; r < 4; r++) {
    float rinv = 1.0f / lrow[r];
    int t = qb * 128 + wave * 16 + quad * 4 + r;
#pragma unroll
    for (int ni = 0; ni < 8; ni++)
      oB[(size_t)t * QSZ + h * 128 + ni * 16 + l15] = f2bf(o[ni][r] * rinv);
  }
}

// ---------------- launch ----------------
extern "C" void kernel_launch(void* const* d_in, const int* in_sizes, int n_in,
                              void* d_out, int out_size, void* d_ws, size_t ws_size,
                              hipStream_t stream) {
  const int*   positions = (const int*)d_in[0];
  const float* hidden    = (const float*)d_in[1];
  const float* w_qkv     = (const float*)d_in[2];
  const float* w_o       = (const float*)d_in[3];
  const float* qw        = (const float*)d_in[4];
  const float* kw        = (const float*)d_in[5];
  float* out = (float*)d_out;
  char*  ws  = (char*)d_ws;

  u16* hiddenB = (u16*)ws;
  u16* wqkvB   = hiddenB + (size_t)HID * HID;
  u16* woB     = wqkvB + (size_t)QKVW * HID;
  size_t off1  = ((size_t)HID * HID + (size_t)QKVW * HID + (size_t)HID * QSZ) * 2;
  float* qkvF  = (float*)(ws + off1);
  u16*   attnB = (u16*)(ws + off1);                          // alias (dead qkvF)
  size_t off2  = off1 + (size_t)T_TOK * QKVW * 4;
  u16* qBuf = (u16*)(ws + off2);
  size_t off3  = off2 + (size_t)T_TOK * QSZ * 2;
  u16* kBuf = (u16*)(ws + off3);
  size_t off4  = off3 + (size_t)T_TOK * KVSZ * 2;
  u16* vTb  = (u16*)(ws + off4);
  size_t off5  = off4 + (size_t)T_TOK * KVSZ * 2;
  u16* vBuf = (u16*)(ws + off5);

  const int n0 = HID * HID / 4, n1 = QKVW * HID / 4, n2 = HID * QSZ / 4;
  cvt3_f32_bf16<<<(n0 + n1 + n2 + 255) / 256, 256, 0, stream>>>(
      hidden, hiddenB, n0, w_qkv, wqkvB, n1, w_o, woB, n2);

  gemm_nt<128><<<dim3(QKVW / 128, T_TOK / 128), 256, 0, stream>>>(hiddenB, wqkvB, qkvF, T_TOK, QKVW, HID);

  norm_rope<<<T_TOK, 256, 0, stream>>>(qkvF, positions, qw, kw, qBuf, kBuf, vBuf);

  transpose_v<<<dim3(T_TOK / 128, NKV), 256, 0, stream>>>(vBuf, vTb);

  attn_fa<<<dim3(T_TOK / 128, NHEADS), 512, 0, stream>>>(qBuf, kBuf, vTb, attnB);

  gemm_nt<64><<<dim3(HID / 128, T_TOK / 64), 256, 0, stream>>>(attnB, woB, out, T_TOK, HID, QSZ);
}

// Round 4
// 355.981 us; speedup vs baseline: 1.4021x; 1.0109x over previous
//
#include <hip/hip_runtime.h>

// ---- problem constants ----
#define T_TOK   2048
#define HID     2048
#define NHEADS  32
#define NKV     4
#define HD      128
#define QSZ     4096          // 32*128
#define KVSZ    512           // 4*128
#define QKVW    5120          // QSZ + 2*KVSZ

typedef unsigned short u16;
typedef __bf16 bf16x8 __attribute__((ext_vector_type(8)));
typedef float  f32x4  __attribute__((ext_vector_type(4)));

__device__ __forceinline__ u16 f2bf(float f) {
  unsigned int u = __float_as_uint(f);
  u += 0x7fffu + ((u >> 16) & 1u);   // RNE
  return (u16)(u >> 16);
}

// native cast path: compiler emits v_cvt_pk_bf16_f32 (RNE, same result)
__device__ __forceinline__ u16 f2bf_n(float f) {
  __bf16 h = (__bf16)f;
  return __builtin_bit_cast(u16, h);
}

// async 16B global -> LDS (wave-uniform base + lane*16 semantics)
__device__ __forceinline__ void gl2lds16(const void* g, void* l) {
  __builtin_amdgcn_global_load_lds(
      (const __attribute__((address_space(1))) unsigned int*)g,
      (__attribute__((address_space(3))) unsigned int*)l, 16, 0, 0);
}

// 16-lane-group reductions via DPP row_ror (VALU latency vs __shfl_xor's
// LDS-pipe ds_swizzle). DPP rows are exactly our 16-lane groups.
template<int N>
__device__ __forceinline__ float rotmax(float x) {
  int t = __builtin_amdgcn_mov_dpp(__float_as_int(x), 0x120 | N, 0xf, 0xf, true);
  return fmaxf(x, __int_as_float(t));
}
template<int N>
__device__ __forceinline__ float rotadd(float x) {
  int t = __builtin_amdgcn_mov_dpp(__float_as_int(x), 0x120 | N, 0xf, 0xf, true);
  return x + __int_as_float(t);
}

// ---------------- fused fp32 -> bf16 convert (3 arrays, one launch) ---------
__global__ void cvt3_f32_bf16(const float* __restrict__ in0, u16* __restrict__ o0, int n0,
                              const float* __restrict__ in1, u16* __restrict__ o1, int n1,
                              const float* __restrict__ in2, u16* __restrict__ o2, int n2) {
  int i = blockIdx.x * blockDim.x + threadIdx.x;
  const float* in; u16* out;
  if (i < n0)            { in = in0; out = o0; }
  else if (i < n0 + n1)  { in = in1; out = o1; i -= n0; }
  else if (i < n0+n1+n2) { in = in2; out = o2; i -= n0 + n1; }
  else return;
  float4 v = ((const float4*)in)[i];
  ushort4 o;
  o.x = f2bf(v.x); o.y = f2bf(v.y); o.z = f2bf(v.z); o.w = f2bf(v.w);
  ((ushort4*)out)[i] = o;
}

// ---------------- NT GEMM: C[m][n] = sum_k A[m][k]*B[n][k] ----------------
// r4: double-buffered LDS + ONE barrier per K-step; next tile's DMA issued
// right after the barrier flies over this tile's ds_read+MFMA (T3 minimum
// 2-phase; same schedule/race-proof as the r2 attention kernel).
// launch_bounds(256,4) caps VGPR at 128 (need ~115) -> 4 blocks/CU with
// 32/24 KB LDS -> 16 waves/CU (was ~2 blocks via (256,2)).
// XCD-aware bijective block swizzle (T1) retained (nwg % 8 == 0: 640, 512).
template<int BM>
__launch_bounds__(256, 4)
__global__ void gemm_nt(const u16* __restrict__ A, const u16* __restrict__ B,
                        float* __restrict__ C, int M, int N, int K) {
  constexpr int MI = BM / 32;          // m-tiles per wave
  __shared__ __align__(16) u16 As[2][BM * 32];
  __shared__ __align__(16) u16 Bs[2][128 * 32];
  const int tid  = threadIdx.x;
  const int wave = tid >> 6, lane = tid & 63;
  const int l15  = lane & 15, quad = lane >> 4;
  const int wr   = wave >> 1, wc = wave & 1;

  const int nwg = gridDim.x * gridDim.y;
  int lid = blockIdx.y * gridDim.x + blockIdx.x;
  lid = (lid & 7) * (nwg >> 3) + (lid >> 3);
  const int bx = lid % gridDim.x;
  const int by = lid / gridDim.x;

  const u16* Ab = A + (size_t)by * BM * K;
  const u16* Bb = B + (size_t)bx * 128 * K;

  f32x4 acc[MI][4];
#pragma unroll
  for (int i = 0; i < MI; i++)
#pragma unroll
    for (int j = 0; j < 4; j++) acc[i][j] = (f32x4){0.f, 0.f, 0.f, 0.f};

  constexpr int ACH = BM * 32 / 8;     // 16B chunks in A tile (multiple of 256)
  // DMA one K-step tile (A: BM x 32, B: 128 x 32) into buf
  auto stage = [&](int t, int buf) {
    const int k0 = t * 32;
#pragma unroll
    for (int s = 0; s < (ACH + 512) / 256; s++) {
      int c = tid + s * 256;
      if (c < ACH) {
        int row = c >> 2, co = (c & 3) * 8;
        gl2lds16(Ab + (size_t)row * K + k0 + co, &As[buf][c * 8]);
      } else {
        int c2 = c - ACH;
        int row = c2 >> 2, co = (c2 & 3) * 8;
        gl2lds16(Bb + (size_t)row * K + k0 + co, &Bs[buf][c2 * 8]);
      }
    }
  };

  const int nst = K / 32;
  stage(0, 0);                         // prologue DMA, tile 0 -> buf 0

  for (int t = 0; t < nst; t++) {
    const int cur = t & 1;
    // barrier: implicit vmcnt(0) drains tile t's DMA; fences buf^1 readers
    __syncthreads();
    // issue next tile's DMA now; it overlaps this tile's ds_read + MFMA
    if (t + 1 < nst) stage(t + 1, cur ^ 1);

    bf16x8 af[MI], bf[4];
#pragma unroll
    for (int i = 0; i < MI; i++) af[i] = *(const bf16x8*)&As[cur][(wr * (BM / 2) + i * 16 + l15) * 32 + quad * 8];
#pragma unroll
    for (int j = 0; j < 4; j++) bf[j] = *(const bf16x8*)&Bs[cur][(wc * 64 + j * 16 + l15) * 32 + quad * 8];
#pragma unroll
    for (int i = 0; i < MI; i++)
#pragma unroll
      for (int j = 0; j < 4; j++)
        acc[i][j] = __builtin_amdgcn_mfma_f32_16x16x32_bf16(af[i], bf[j], acc[i][j], 0, 0, 0);
  }

  float* Cb = C + (size_t)by * BM * N + (size_t)bx * 128;
#pragma unroll
  for (int i = 0; i < MI; i++) {
    int rbase = wr * (BM / 2) + i * 16 + quad * 4;
#pragma unroll
    for (int j = 0; j < 4; j++) {
      int col = wc * 64 + j * 16 + l15;
#pragma unroll
      for (int r = 0; r < 4; r++) Cb[(size_t)(rbase + r) * N + col] = acc[i][j][r];
    }
  }
}

// ---------------- RMSNorm + RoPE + cast (one block per token) ----------------
// q additionally folds log2(e) so attention scores arrive in the exp2 domain
// (softmax then uses raw v_exp_f32 with no per-element log2e multiply).
__global__ void norm_rope(const float* __restrict__ qkv, const int* __restrict__ pos,
                          const float* __restrict__ qw, const float* __restrict__ kw,
                          u16* __restrict__ qB, u16* __restrict__ kB, u16* __restrict__ vB) {
  const int t = blockIdx.x;
  const int wave = threadIdx.x >> 6, l = threadIdx.x & 63;
  const float* row = qkv + (size_t)t * QKVW;

  constexpr float QSC = 0.08838834764831845f * 1.4426950408889634f; // 1/sqrt(HD) * log2(e)

  const float p = (float)pos[t];
  const float fr = p * exp2f(-(float)l * 0.20762050593046014f);
  float sn, cs;
  sincosf(fr, &sn, &cs);

  for (int slot = wave; slot < 40; slot += 4) {
    if (slot < 36) {
      const int   base = (slot < 32) ? slot * 128 : 4096 + (slot - 32) * 128;
      const float* w   = (slot < 32) ? qw : kw;
      float x1 = row[base + l], x2 = row[base + 64 + l];
      float ss = x1 * x1 + x2 * x2;
#pragma unroll
      for (int off = 32; off; off >>= 1) ss += __shfl_xor(ss, off);
      float rs = rsqrtf(ss * (1.f / 128.f) + 1e-6f);
      float n1 = x1 * rs * w[l], n2 = x2 * rs * w[64 + l];
      float o1 = n1 * cs - n2 * sn;
      float o2 = n2 * cs + n1 * sn;
      if (slot < 32) {
        o1 *= QSC;
        o2 *= QSC;
        qB[(size_t)t * QSZ + slot * 128 + l]      = f2bf(o1);
        qB[(size_t)t * QSZ + slot * 128 + 64 + l] = f2bf(o2);
      } else {
        kB[(size_t)t * KVSZ + (slot - 32) * 128 + l]      = f2bf(o1);
        kB[(size_t)t * KVSZ + (slot - 32) * 128 + 64 + l] = f2bf(o2);
      }
    } else {
      int vh = slot - 36;
      float x1 = row[4608 + vh * 128 + l];
      float x2 = row[4608 + vh * 128 + 64 + l];
      vB[(size_t)t * KVSZ + vh * 128 + l]      = f2bf(x1);
      vB[(size_t)t * KVSZ + vh * 128 + 64 + l] = f2bf(x2);
    }
  }
}

// ---------------- V transpose: vB[t][kvh*128+d] -> vT[kvh*128+d][t] ---------
__global__ void transpose_v(const u16* __restrict__ vB, u16* __restrict__ vT) {
  const int vh = blockIdx.y, tb = blockIdx.x;
  const int d0 = threadIdx.x >> 4;          // + s*16
  const int tc = (threadIdx.x & 15) * 8;
#pragma unroll
  for (int s = 0; s < 8; s++) {
    int dd = d0 + s * 16;
    uint4 v; u16* pv = (u16*)&v;
#pragma unroll
    for (int j = 0; j < 8; j++)
      pv[j] = vB[(size_t)(tb * 128 + tc + j) * KVSZ + vh * 128 + dd];
    *(uint4*)&vT[((size_t)vh * 128 + dd) * T_TOK + tb * 128 + tc] = v;
  }
}

// ---------------- flash attention (causal, GQA 8:1) -------------------------
// r2 structure (memory-clean, spill-free): 512 thr / 8 waves, 128-row
// q-strips, 64-key tiles, double-buffered K/V via global_load_lds with
// PRE-SWIZZLED global source (rule #21), one barrier/tile, x-reversal
// pairing (uniform 34 tile-units/CU). r3: DPP rotate-reduce softmax,
// exp2-domain (log2e folded into q), epilogue rcp. r4: native bf16 casts
// (packed v_cvt_pk_bf16_f32) replace manual bit-twiddle in hot paths.
__launch_bounds__(512, 4)
__global__ void attn_fa(const u16* __restrict__ qB, const u16* __restrict__ kB,
                        const u16* __restrict__ vT, u16* __restrict__ oB) {
  const int qb  = (blockIdx.y < 16) ? (15 - (int)blockIdx.x) : (int)blockIdx.x;
  const int h   = blockIdx.y;
  const int kvh = h >> 3;
  __shared__ __align__(16) u16 Kb[2][64 * 16 * 8];   // [key][d], swizzled, 16 KB each
  __shared__ __align__(16) u16 Vb[2][128 * 8 * 8];   // [d][key], swizzled, 16 KB each
  __shared__ __align__(16) u16 Pb[128 * 8 * 8];      // [row][key], swizzled, 16 KB

  const int tid  = threadIdx.x;
  const int wave = tid >> 6, lane = tid & 63;
  const int l15  = lane & 15, quad = lane >> 4;

  // DMA one 64-key tile (K: [key][d] 16KB, V^T: [d][key] 16KB) into buf.
  // Linear LDS chunk c receives global chunk (c&mask)^(row&mask): the same
  // XOR involution the reads use, so read-side swizzles are unchanged.
  auto stage = [&](int kt, int buf) {
#pragma unroll
    for (int s = 0; s < 2; s++) {
      int c = tid + s * 512;                 // 16B chunk id, 0..1023
      int r = c >> 4;                        // key row 0..63
      gl2lds16(kB + (size_t)(kt * 64 + r) * KVSZ + kvh * 128 + ((c & 15) ^ (r & 15)) * 8,
               &Kb[buf][c * 8]);
    }
#pragma unroll
    for (int s = 0; s < 2; s++) {
      int c = tid + s * 512;                 // 16B chunk id, 0..1023
      int rv = c >> 3;                       // d row 0..127
      gl2lds16(vT + ((size_t)kvh * 128 + rv) * T_TOK + kt * 64 + ((c & 7) ^ (rv & 7)) * 8,
               &Vb[buf][c * 8]);
    }
  };

  bf16x8 qf[4];
#pragma unroll
  for (int ds = 0; ds < 4; ds++)
    qf[ds] = *(const bf16x8*)(qB + (size_t)(qb * 128 + wave * 16 + l15) * QSZ
                                 + h * 128 + ds * 32 + quad * 8);

  f32x4 o[8];
#pragma unroll
  for (int ni = 0; ni < 8; ni++) o[ni] = (f32x4){0.f, 0.f, 0.f, 0.f};
  float mrow[4], lrow[4];
#pragma unroll
  for (int r = 0; r < 4; r++) { mrow[r] = -3.0e38f; lrow[r] = 0.f; }

  const int nt = 2 * qb + 2;                   // 64-key tiles

  stage(0, 0);                                 // prologue DMA, tile 0 -> buf 0

  for (int kt = 0; kt < nt; kt++) {
    const int cur = kt & 1;
    // barrier: implicit vmcnt(0) drains tile kt's DMA for THIS wave, then
    // s_barrier makes every wave's DMA visible; also fences buf^1 readers.
    __syncthreads();
    // issue next tile's DMA now; it overlaps this whole tile's compute
    if (kt + 1 < nt) stage(kt + 1, cur ^ 1);

    // S = Q K^T (16 rows x 64 keys per wave)
    f32x4 sc[4];
#pragma unroll
    for (int ni = 0; ni < 4; ni++) sc[ni] = (f32x4){0.f, 0.f, 0.f, 0.f};
    __builtin_amdgcn_s_setprio(1);
#pragma unroll
    for (int ds = 0; ds < 4; ds++) {
#pragma unroll
      for (int ni = 0; ni < 4; ni++) {
        bf16x8 kf = *(const bf16x8*)&Kb[cur][((ni * 16 + l15) * 16 + ((ds * 4 + quad) ^ l15)) * 8];
        sc[ni] = __builtin_amdgcn_mfma_f32_16x16x32_bf16(qf[ds], kf, sc[ni], 0, 0, 0);
      }
    }
    __builtin_amdgcn_s_setprio(0);

    if (kt >= 2 * qb) {  // tiles intersecting the diagonal
#pragma unroll
      for (int ni = 0; ni < 4; ni++)
#pragma unroll
        for (int r = 0; r < 4; r++) {
          int key = kt * 64 + ni * 16 + l15;
          int rw  = qb * 128 + wave * 16 + quad * 4 + r;
          if (key > rw) sc[ni][r] = -1.0e30f;
        }
    }

    // online softmax in exp2 domain (stats per 16-lane row-group),
    // defer-max THR=8 (P bounded by 2^8), DPP rotate-reduce.
#pragma unroll
    for (int r = 0; r < 4; r++) {
      float mx = fmaxf(fmaxf(sc[0][r], sc[1][r]), fmaxf(sc[2][r], sc[3][r]));
      mx = rotmax<1>(mx); mx = rotmax<2>(mx); mx = rotmax<4>(mx); mx = rotmax<8>(mx);
      if (!__all(mx <= mrow[r] + 8.f)) {
        float mn = fmaxf(mrow[r], mx);
        float al = exp2f(mrow[r] - mn);
        mrow[r]  = mn;
        lrow[r] *= al;
#pragma unroll
        for (int ni = 0; ni < 8; ni++) o[ni][r] *= al;
      }
      float rs = 0.f;
#pragma unroll
      for (int ni = 0; ni < 4; ni++) {
        float pv = exp2f(sc[ni][r] - mrow[r]);
        sc[ni][r] = pv;
        rs += pv;
      }
      rs = rotadd<1>(rs); rs = rotadd<2>(rs); rs = rotadd<4>(rs); rs = rotadd<8>(rs);
      lrow[r] += rs;
    }

    // P (own 16-row strip) -> swizzled Pb; strip-private => no barrier
#pragma unroll
    for (int ni = 0; ni < 4; ni++)
#pragma unroll
      for (int r = 0; r < 4; r++) {
        int row = wave * 16 + quad * 4 + r;
        Pb[(row * 8 + ((ni * 2 + (l15 >> 3)) ^ (row & 7))) * 8 + (l15 & 7)] =
            f2bf_n(sc[ni][r]);
      }

    // O += P V  (A = own P strip, B = V^T tile)
    __builtin_amdgcn_s_setprio(1);
#pragma unroll
    for (int ks = 0; ks < 2; ks++) {
      bf16x8 pf = *(const bf16x8*)&Pb[((wave * 16 + l15) * 8 + ((ks * 4 + quad) ^ (l15 & 7))) * 8];
#pragma unroll
      for (int ni = 0; ni < 8; ni++) {
        bf16x8 vf = *(const bf16x8*)&Vb[cur][((ni * 16 + l15) * 8 + ((ks * 4 + quad) ^ (l15 & 7))) * 8];
        o[ni] = __builtin_amdgcn_mfma_f32_16x16x32_bf16(pf, vf, o[ni], 0, 0, 0);
      }
    }
    __builtin_amdgcn_s_setprio(0);
  }

  // epilogue: O * (1/l) -> bf16 (4 divides instead of 32)
#pragma unroll
  for (int r = 0; r < 4; r++) {
    float rinv = 1.0f / lrow[r];
    int t = qb * 128 + wave * 16 + quad * 4 + r;
#pragma unroll
    for (int ni = 0; ni < 8; ni++)
      oB[(size_t)t * QSZ + h * 128 + ni * 16 + l15] = f2bf_n(o[ni][r] * rinv);
  }
}

// ---------------- launch ----------------
extern "C" void kernel_launch(void* const* d_in, const int* in_sizes, int n_in,
                              void* d_out, int out_size, void* d_ws, size_t ws_size,
                              hipStream_t stream) {
  const int*   positions = (const int*)d_in[0];
  const float* hidden    = (const float*)d_in[1];
  const float* w_qkv     = (const float*)d_in[2];
  const float* w_o       = (const float*)d_in[3];
  const float* qw        = (const float*)d_in[4];
  const float* kw        = (const float*)d_in[5];
  float* out = (float*)d_out;
  char*  ws  = (char*)d_ws;

  u16* hiddenB = (u16*)ws;
  u16* wqkvB   = hiddenB + (size_t)HID * HID;
  u16* woB     = wqkvB + (size_t)QKVW * HID;
  size_t off1  = ((size_t)HID * HID + (size_t)QKVW * HID + (size_t)HID * QSZ) * 2;
  float* qkvF  = (float*)(ws + off1);
  u16*   attnB = (u16*)(ws + off1);                          // alias (dead qkvF)
  size_t off2  = off1 + (size_t)T_TOK * QKVW * 4;
  u16* qBuf = (u16*)(ws + off2);
  size_t off3  = off2 + (size_t)T_TOK * QSZ * 2;
  u16* kBuf = (u16*)(ws + off3);
  size_t off4  = off3 + (size_t)T_TOK * KVSZ * 2;
  u16* vTb  = (u16*)(ws + off4);
  size_t off5  = off4 + (size_t)T_TOK * KVSZ * 2;
  u16* vBuf = (u16*)(ws + off5);

  const int n0 = HID * HID / 4, n1 = QKVW * HID / 4, n2 = HID * QSZ / 4;
  cvt3_f32_bf16<<<(n0 + n1 + n2 + 255) / 256, 256, 0, stream>>>(
      hidden, hiddenB, n0, w_qkv, wqkvB, n1, w_o, woB, n2);

  gemm_nt<128><<<dim3(QKVW / 128, T_TOK / 128), 256, 0, stream>>>(hiddenB, wqkvB, qkvF, T_TOK, QKVW, HID);

  norm_rope<<<T_TOK, 256, 0, stream>>>(qkvF, positions, qw, kw, qBuf, kBuf, vBuf);

  transpose_v<<<dim3(T_TOK / 128, NKV), 256, 0, stream>>>(vBuf, vTb);

  attn_fa<<<dim3(T_TOK / 128, NHEADS), 512, 0, stream>>>(qBuf, kBuf, vTb, attnB);

  gemm_nt<64><<<dim3(HID / 128, T_TOK / 64), 256, 0, stream>>>(attnB, woB, out, T_TOK, HID, QSZ);
}

// Round 5
// 349.158 us; speedup vs baseline: 1.4295x; 1.0195x over previous
//
#include <hip/hip_runtime.h>

// ---- problem constants ----
#define T_TOK   2048
#define HID     2048
#define NHEADS  32
#define NKV     4
#define HD      128
#define QSZ     4096          // 32*128
#define KVSZ    512           // 4*128
#define QKVW    5120          // QSZ + 2*KVSZ

typedef unsigned short u16;
typedef __bf16 bf16x8 __attribute__((ext_vector_type(8)));
typedef float  f32x4  __attribute__((ext_vector_type(4)));

__device__ __forceinline__ u16 f2bf(float f) {
  unsigned int u = __float_as_uint(f);
  u += 0x7fffu + ((u >> 16) & 1u);   // RNE
  return (u16)(u >> 16);
}

// native cast path: compiler emits v_cvt_pk_bf16_f32 (RNE, same result)
__device__ __forceinline__ u16 f2bf_n(float f) {
  __bf16 h = (__bf16)f;
  return __builtin_bit_cast(u16, h);
}

// async 16B global -> LDS (wave-uniform base + lane*16 semantics)
__device__ __forceinline__ void gl2lds16(const void* g, void* l) {
  __builtin_amdgcn_global_load_lds(
      (const __attribute__((address_space(1))) unsigned int*)g,
      (__attribute__((address_space(3))) unsigned int*)l, 16, 0, 0);
}

// 16-lane-group reductions via DPP row_ror (VALU latency vs __shfl_xor's
// LDS-pipe ds_swizzle). DPP rows are exactly our 16-lane groups.
template<int N>
__device__ __forceinline__ float rotmax(float x) {
  int t = __builtin_amdgcn_mov_dpp(__float_as_int(x), 0x120 | N, 0xf, 0xf, true);
  return fmaxf(x, __int_as_float(t));
}
template<int N>
__device__ __forceinline__ float rotadd(float x) {
  int t = __builtin_amdgcn_mov_dpp(__float_as_int(x), 0x120 | N, 0xf, 0xf, true);
  return x + __int_as_float(t);
}

// ---------------- fused fp32 -> bf16 convert (3 arrays, one launch) ---------
__global__ void cvt3_f32_bf16(const float* __restrict__ in0, u16* __restrict__ o0, int n0,
                              const float* __restrict__ in1, u16* __restrict__ o1, int n1,
                              const float* __restrict__ in2, u16* __restrict__ o2, int n2) {
  int i = blockIdx.x * blockDim.x + threadIdx.x;
  const float* in; u16* out;
  if (i < n0)            { in = in0; out = o0; }
  else if (i < n0 + n1)  { in = in1; out = o1; i -= n0; }
  else if (i < n0+n1+n2) { in = in2; out = o2; i -= n0 + n1; }
  else return;
  float4 v = ((const float4*)in)[i];
  ushort4 o;
  o.x = f2bf(v.x); o.y = f2bf(v.y); o.z = f2bf(v.z); o.w = f2bf(v.w);
  ((ushort4*)out)[i] = o;
}

// ---------------- NT GEMM: C[m][n] = sum_k A[m][k]*B[n][k] ----------------
// Double-buffered LDS + one barrier per K-step (T3 minimum 2-phase); DMA of
// tile t+1 issued right after the barrier flies over tile t's ds_read+MFMA.
// launch_bounds(256,4): VGPR cap 128 (need ~115) -> 4 blocks/CU.
// XCD-aware bijective block swizzle (T1; nwg % 8 == 0: 640, 512).
template<int BM>
__launch_bounds__(256, 4)
__global__ void gemm_nt(const u16* __restrict__ A, const u16* __restrict__ B,
                        float* __restrict__ C, int M, int N, int K) {
  constexpr int MI = BM / 32;          // m-tiles per wave
  __shared__ __align__(16) u16 As[2][BM * 32];
  __shared__ __align__(16) u16 Bs[2][128 * 32];
  const int tid  = threadIdx.x;
  const int wave = tid >> 6, lane = tid & 63;
  const int l15  = lane & 15, quad = lane >> 4;
  const int wr   = wave >> 1, wc = wave & 1;

  const int nwg = gridDim.x * gridDim.y;
  int lid = blockIdx.y * gridDim.x + blockIdx.x;
  lid = (lid & 7) * (nwg >> 3) + (lid >> 3);
  const int bx = lid % gridDim.x;
  const int by = lid / gridDim.x;

  const u16* Ab = A + (size_t)by * BM * K;
  const u16* Bb = B + (size_t)bx * 128 * K;

  f32x4 acc[MI][4];
#pragma unroll
  for (int i = 0; i < MI; i++)
#pragma unroll
    for (int j = 0; j < 4; j++) acc[i][j] = (f32x4){0.f, 0.f, 0.f, 0.f};

  constexpr int ACH = BM * 32 / 8;     // 16B chunks in A tile (multiple of 256)
  auto stage = [&](int t, int buf) {
    const int k0 = t * 32;
#pragma unroll
    for (int s = 0; s < (ACH + 512) / 256; s++) {
      int c = tid + s * 256;
      if (c < ACH) {
        int row = c >> 2, co = (c & 3) * 8;
        gl2lds16(Ab + (size_t)row * K + k0 + co, &As[buf][c * 8]);
      } else {
        int c2 = c - ACH;
        int row = c2 >> 2, co = (c2 & 3) * 8;
        gl2lds16(Bb + (size_t)row * K + k0 + co, &Bs[buf][c2 * 8]);
      }
    }
  };

  const int nst = K / 32;
  stage(0, 0);                         // prologue DMA, tile 0 -> buf 0

  for (int t = 0; t < nst; t++) {
    const int cur = t & 1;
    __syncthreads();                   // drains tile t's DMA; fences buf^1
    if (t + 1 < nst) stage(t + 1, cur ^ 1);

    bf16x8 af[MI], bf[4];
#pragma unroll
    for (int i = 0; i < MI; i++) af[i] = *(const bf16x8*)&As[cur][(wr * (BM / 2) + i * 16 + l15) * 32 + quad * 8];
#pragma unroll
    for (int j = 0; j < 4; j++) bf[j] = *(const bf16x8*)&Bs[cur][(wc * 64 + j * 16 + l15) * 32 + quad * 8];
#pragma unroll
    for (int i = 0; i < MI; i++)
#pragma unroll
      for (int j = 0; j < 4; j++)
        acc[i][j] = __builtin_amdgcn_mfma_f32_16x16x32_bf16(af[i], bf[j], acc[i][j], 0, 0, 0);
  }

  float* Cb = C + (size_t)by * BM * N + (size_t)bx * 128;
#pragma unroll
  for (int i = 0; i < MI; i++) {
    int rbase = wr * (BM / 2) + i * 16 + quad * 4;
#pragma unroll
    for (int j = 0; j < 4; j++) {
      int col = wc * 64 + j * 16 + l15;
#pragma unroll
      for (int r = 0; r < 4; r++) Cb[(size_t)(rbase + r) * N + col] = acc[i][j][r];
    }
  }
}

// ---------------- RMSNorm + RoPE + cast (one block per token) ----------------
// q additionally folds log2(e) so attention scores arrive in the exp2 domain.
__global__ void norm_rope(const float* __restrict__ qkv, const int* __restrict__ pos,
                          const float* __restrict__ qw, const float* __restrict__ kw,
                          u16* __restrict__ qB, u16* __restrict__ kB, u16* __restrict__ vB) {
  const int t = blockIdx.x;
  const int wave = threadIdx.x >> 6, l = threadIdx.x & 63;
  const float* row = qkv + (size_t)t * QKVW;

  constexpr float QSC = 0.08838834764831845f * 1.4426950408889634f; // 1/sqrt(HD) * log2(e)

  const float p = (float)pos[t];
  const float fr = p * exp2f(-(float)l * 0.20762050593046014f);
  float sn, cs;
  sincosf(fr, &sn, &cs);

  for (int slot = wave; slot < 40; slot += 4) {
    if (slot < 36) {
      const int   base = (slot < 32) ? slot * 128 : 4096 + (slot - 32) * 128;
      const float* w   = (slot < 32) ? qw : kw;
      float x1 = row[base + l], x2 = row[base + 64 + l];
      float ss = x1 * x1 + x2 * x2;
#pragma unroll
      for (int off = 32; off; off >>= 1) ss += __shfl_xor(ss, off);
      float rs = rsqrtf(ss * (1.f / 128.f) + 1e-6f);
      float n1 = x1 * rs * w[l], n2 = x2 * rs * w[64 + l];
      float o1 = n1 * cs - n2 * sn;
      float o2 = n2 * cs + n1 * sn;
      if (slot < 32) {
        o1 *= QSC;
        o2 *= QSC;
        qB[(size_t)t * QSZ + slot * 128 + l]      = f2bf(o1);
        qB[(size_t)t * QSZ + slot * 128 + 64 + l] = f2bf(o2);
      } else {
        kB[(size_t)t * KVSZ + (slot - 32) * 128 + l]      = f2bf(o1);
        kB[(size_t)t * KVSZ + (slot - 32) * 128 + 64 + l] = f2bf(o2);
      }
    } else {
      int vh = slot - 36;
      float x1 = row[4608 + vh * 128 + l];
      float x2 = row[4608 + vh * 128 + 64 + l];
      vB[(size_t)t * KVSZ + vh * 128 + l]      = f2bf(x1);
      vB[(size_t)t * KVSZ + vh * 128 + 64 + l] = f2bf(x2);
    }
  }
}

// ---------------- V transpose: vB (2048 x 512 u16) -> vT (512 x 2048 u16) ---
// r5: LDS-tiled 64x64 transpose, grid (32,8)=256 blocks (was 64 blocks doing
// 64 scattered 2B global reads/thread -> latency-bound on 1/4 of the CUs).
// Row stride 65 (odd) -> both the row-scatter writes and column gathers
// spread across banks (~2-way, free per m136). Global I/O fully uint4.
__global__ void transpose_v(const u16* __restrict__ vB, u16* __restrict__ vT) {
  __shared__ u16 Ld[64 * 65];
  const int tb = blockIdx.x;                // token tile (64 wide)
  const int db = blockIdx.y;                // d tile (64 wide, over KVSZ=512)
  const int tid = threadIdx.x;
  const int r  = tid >> 3;                  // 0..31 (+s*32)
  const int c8 = (tid & 7) * 8;             // 0..56
#pragma unroll
  for (int s = 0; s < 2; s++) {
    int tr = r + s * 32;                    // token row in tile
    uint4 v = *(const uint4*)&vB[(size_t)(tb * 64 + tr) * KVSZ + db * 64 + c8];
    const u16* pv = (const u16*)&v;
#pragma unroll
    for (int j = 0; j < 8; j++) Ld[tr * 65 + c8 + j] = pv[j];
  }
  __syncthreads();
#pragma unroll
  for (int s = 0; s < 2; s++) {
    int dr = r + s * 32;                    // d row in tile
    uint4 v; u16* pv = (u16*)&v;
#pragma unroll
    for (int j = 0; j < 8; j++) pv[j] = Ld[(c8 + j) * 65 + dr];
    *(uint4*)&vT[(size_t)(db * 64 + dr) * T_TOK + tb * 64 + c8] = v;
  }
}

// ---------------- flash attention (causal, GQA 8:1) -------------------------
// r2 structure (memory-clean, spill-free): 512 thr / 8 waves, 128-row
// q-strips, 64-key tiles, double-buffered K/V via global_load_lds with
// PRE-SWIZZLED global source (rule #21), one barrier/tile, x-reversal
// pairing (uniform 36 tile-units/CU). r3: DPP rotate-reduce softmax,
// exp2-domain. r4: native bf16 casts. r5: DEFERRED l-sum — lrow is a
// per-lane partial (rescale factor al is group-uniform so partials stay
// consistent); the 16-lane sum-reduce happens ONCE in the epilogue,
// removing 4 dependent rotadd chains per tile.
__launch_bounds__(512, 4)
__global__ void attn_fa(const u16* __restrict__ qB, const u16* __restrict__ kB,
                        const u16* __restrict__ vT, u16* __restrict__ oB) {
  const int qb  = (blockIdx.y < 16) ? (15 - (int)blockIdx.x) : (int)blockIdx.x;
  const int h   = blockIdx.y;
  const int kvh = h >> 3;
  __shared__ __align__(16) u16 Kb[2][64 * 16 * 8];   // [key][d], swizzled, 16 KB each
  __shared__ __align__(16) u16 Vb[2][128 * 8 * 8];   // [d][key], swizzled, 16 KB each
  __shared__ __align__(16) u16 Pb[128 * 8 * 8];      // [row][key], swizzled, 16 KB

  const int tid  = threadIdx.x;
  const int wave = tid >> 6, lane = tid & 63;
  const int l15  = lane & 15, quad = lane >> 4;

  // DMA one 64-key tile (K: [key][d] 16KB, V^T: [d][key] 16KB) into buf.
  // Linear LDS chunk c receives global chunk (c&mask)^(row&mask): the same
  // XOR involution the reads use, so read-side swizzles are unchanged.
  auto stage = [&](int kt, int buf) {
#pragma unroll
    for (int s = 0; s < 2; s++) {
      int c = tid + s * 512;                 // 16B chunk id, 0..1023
      int r = c >> 4;                        // key row 0..63
      gl2lds16(kB + (size_t)(kt * 64 + r) * KVSZ + kvh * 128 + ((c & 15) ^ (r & 15)) * 8,
               &Kb[buf][c * 8]);
    }
#pragma unroll
    for (int s = 0; s < 2; s++) {
      int c = tid + s * 512;                 // 16B chunk id, 0..1023
      int rv = c >> 3;                       // d row 0..127
      gl2lds16(vT + ((size_t)kvh * 128 + rv) * T_TOK + kt * 64 + ((c & 7) ^ (rv & 7)) * 8,
               &Vb[buf][c * 8]);
    }
  };

  bf16x8 qf[4];
#pragma unroll
  for (int ds = 0; ds < 4; ds++)
    qf[ds] = *(const bf16x8*)(qB + (size_t)(qb * 128 + wave * 16 + l15) * QSZ
                                 + h * 128 + ds * 32 + quad * 8);

  f32x4 o[8];
#pragma unroll
  for (int ni = 0; ni < 8; ni++) o[ni] = (f32x4){0.f, 0.f, 0.f, 0.f};
  float mrow[4], lrow[4];
#pragma unroll
  for (int r = 0; r < 4; r++) { mrow[r] = -3.0e38f; lrow[r] = 0.f; }

  const int nt = 2 * qb + 2;                   // 64-key tiles

  stage(0, 0);                                 // prologue DMA, tile 0 -> buf 0

  for (int kt = 0; kt < nt; kt++) {
    const int cur = kt & 1;
    // barrier: implicit vmcnt(0) drains tile kt's DMA for THIS wave, then
    // s_barrier makes every wave's DMA visible; also fences buf^1 readers.
    __syncthreads();
    // issue next tile's DMA now; it overlaps this whole tile's compute
    if (kt + 1 < nt) stage(kt + 1, cur ^ 1);

    // S = Q K^T (16 rows x 64 keys per wave)
    f32x4 sc[4];
#pragma unroll
    for (int ni = 0; ni < 4; ni++) sc[ni] = (f32x4){0.f, 0.f, 0.f, 0.f};
    __builtin_amdgcn_s_setprio(1);
#pragma unroll
    for (int ds = 0; ds < 4; ds++) {
#pragma unroll
      for (int ni = 0; ni < 4; ni++) {
        bf16x8 kf = *(const bf16x8*)&Kb[cur][((ni * 16 + l15) * 16 + ((ds * 4 + quad) ^ l15)) * 8];
        sc[ni] = __builtin_amdgcn_mfma_f32_16x16x32_bf16(qf[ds], kf, sc[ni], 0, 0, 0);
      }
    }
    __builtin_amdgcn_s_setprio(0);

    if (kt >= 2 * qb) {  // tiles intersecting the diagonal
#pragma unroll
      for (int ni = 0; ni < 4; ni++)
#pragma unroll
        for (int r = 0; r < 4; r++) {
          int key = kt * 64 + ni * 16 + l15;
          int rw  = qb * 128 + wave * 16 + quad * 4 + r;
          if (key > rw) sc[ni][r] = -1.0e30f;
        }
    }

    // online softmax in exp2 domain (stats per 16-lane row-group),
    // defer-max THR=8, DPP rotate-reduce for max; l-sum kept PER-LANE.
#pragma unroll
    for (int r = 0; r < 4; r++) {
      float mx = fmaxf(fmaxf(sc[0][r], sc[1][r]), fmaxf(sc[2][r], sc[3][r]));
      mx = rotmax<1>(mx); mx = rotmax<2>(mx); mx = rotmax<4>(mx); mx = rotmax<8>(mx);
      if (!__all(mx <= mrow[r] + 8.f)) {
        float mn = fmaxf(mrow[r], mx);
        float al = exp2f(mrow[r] - mn);      // group-uniform
        mrow[r]  = mn;
        lrow[r] *= al;                       // per-lane partial stays consistent
#pragma unroll
        for (int ni = 0; ni < 8; ni++) o[ni][r] *= al;
      }
      float rs = 0.f;
#pragma unroll
      for (int ni = 0; ni < 4; ni++) {
        float pv = exp2f(sc[ni][r] - mrow[r]);
        sc[ni][r] = pv;
        rs += pv;
      }
      lrow[r] += rs;                         // no cross-lane reduce here
    }

    // P (own 16-row strip) -> swizzled Pb; strip-private => no barrier
#pragma unroll
    for (int ni = 0; ni < 4; ni++)
#pragma unroll
      for (int r = 0; r < 4; r++) {
        int row = wave * 16 + quad * 4 + r;
        Pb[(row * 8 + ((ni * 2 + (l15 >> 3)) ^ (row & 7))) * 8 + (l15 & 7)] =
            f2bf_n(sc[ni][r]);
      }

    // O += P V  (A = own P strip, B = V^T tile)
    __builtin_amdgcn_s_setprio(1);
#pragma unroll
    for (int ks = 0; ks < 2; ks++) {
      bf16x8 pf = *(const bf16x8*)&Pb[((wave * 16 + l15) * 8 + ((ks * 4 + quad) ^ (l15 & 7))) * 8];
#pragma unroll
      for (int ni = 0; ni < 8; ni++) {
        bf16x8 vf = *(const bf16x8*)&Vb[cur][((ni * 16 + l15) * 8 + ((ks * 4 + quad) ^ (l15 & 7))) * 8];
        o[ni] = __builtin_amdgcn_mfma_f32_16x16x32_bf16(pf, vf, o[ni], 0, 0, 0);
      }
    }
    __builtin_amdgcn_s_setprio(0);
  }

  // epilogue: reduce the deferred per-lane l partials ONCE, then O * (1/l)
#pragma unroll
  for (int r = 0; r < 4; r++) {
    float s = lrow[r];
    s = rotadd<1>(s); s = rotadd<2>(s); s = rotadd<4>(s); s = rotadd<8>(s);
    float rinv = 1.0f / s;
    int t = qb * 128 + wave * 16 + quad * 4 + r;
#pragma unroll
    for (int ni = 0; ni < 8; ni++)
      oB[(size_t)t * QSZ + h * 128 + ni * 16 + l15] = f2bf_n(o[ni][r] * rinv);
  }
}

// ---------------- launch ----------------
extern "C" void kernel_launch(void* const* d_in, const int* in_sizes, int n_in,
                              void* d_out, int out_size, void* d_ws, size_t ws_size,
                              hipStream_t stream) {
  const int*   positions = (const int*)d_in[0];
  const float* hidden    = (const float*)d_in[1];
  const float* w_qkv     = (const float*)d_in[2];
  const float* w_o       = (const float*)d_in[3];
  const float* qw        = (const float*)d_in[4];
  const float* kw        = (const float*)d_in[5];
  float* out = (float*)d_out;
  char*  ws  = (char*)d_ws;

  u16* hiddenB = (u16*)ws;
  u16* wqkvB   = hiddenB + (size_t)HID * HID;
  u16* woB     = wqkvB + (size_t)QKVW * HID;
  size_t off1  = ((size_t)HID * HID + (size_t)QKVW * HID + (size_t)HID * QSZ) * 2;
  float* qkvF  = (float*)(ws + off1);
  u16*   attnB = (u16*)(ws + off1);                          // alias (dead qkvF)
  size_t off2  = off1 + (size_t)T_TOK * QKVW * 4;
  u16* qBuf = (u16*)(ws + off2);
  size_t off3  = off2 + (size_t)T_TOK * QSZ * 2;
  u16* kBuf = (u16*)(ws + off3);
  size_t off4  = off3 + (size_t)T_TOK * KVSZ * 2;
  u16* vTb  = (u16*)(ws + off4);
  size_t off5  = off4 + (size_t)T_TOK * KVSZ * 2;
  u16* vBuf = (u16*)(ws + off5);

  const int n0 = HID * HID / 4, n1 = QKVW * HID / 4, n2 = HID * QSZ / 4;
  cvt3_f32_bf16<<<(n0 + n1 + n2 + 255) / 256, 256, 0, stream>>>(
      hidden, hiddenB, n0, w_qkv, wqkvB, n1, w_o, woB, n2);

  gemm_nt<128><<<dim3(QKVW / 128, T_TOK / 128), 256, 0, stream>>>(hiddenB, wqkvB, qkvF, T_TOK, QKVW, HID);

  norm_rope<<<T_TOK, 256, 0, stream>>>(qkvF, positions, qw, kw, qBuf, kBuf, vBuf);

  transpose_v<<<dim3(T_TOK / 64, KVSZ / 64), 256, 0, stream>>>(vBuf, vTb);

  attn_fa<<<dim3(T_TOK / 128, NHEADS), 512, 0, stream>>>(qBuf, kBuf, vTb, attnB);

  gemm_nt<64><<<dim3(HID / 128, T_TOK / 64), 256, 0, stream>>>(attnB, woB, out, T_TOK, HID, QSZ);
}